// Round 2
// baseline (472.111 us; speedup 1.0000x reference)
//
#include <hip/hip_runtime.h>
#include <math.h>

#define NC    10
#define BATCH 256
#define IC    1152
#define LDIM  8
#define OC    16

// k2 geometry: block = (n, 4 b's, 1/3 of IC) -> 1920 blocks (~7.5/CU, one round)
#define BGRP2 4
#define ICCH2 3
#define CHSZ2 (IC/ICCH2)            // 384
#define NBG2  (BATCH/BGRP2)         // 64
#define NBLK2 (NC*NBG2*ICCH2)       // 1920, %8==0 -> bijective swizzle

// k4 geometry: block = (n, 2 b's, 1/2 of IC) -> 2560 blocks, v regs = 32
#define BGRP4 2
#define ICCH4 2
#define CHSZ4 (IC/ICCH4)            // 576
#define NBG4  (BATCH/BGRP4)         // 128
#define NBLK4 (NC*NBG4*ICCH4)       // 2560

__device__ __forceinline__ int xcd_swizzle(int bid, int nwg) {
    int cpx = nwg >> 3;
    return (bid & 7) * cpx + (bid >> 3);
}

// ---------------------------------------------------------------------------
// K2: s_part[chunk][n,b,o] = sum_{i in chunk} c[n,b,i] * priors[n,b,i,o]
//     priors recomputed on the fly; c = exp(beta)/denom (or 1/256 on iter 0)
// ---------------------------------------------------------------------------
template<bool ITER0>
__global__ __launch_bounds__(256) void k2_s(
    const float* __restrict__ x, const float* __restrict__ w,
    const float* __restrict__ beta, const float* __restrict__ denom,
    float* __restrict__ s_part)
{
    __shared__ float c_lds[BGRP2][CHSZ2];   // 6 KB
    __shared__ float red[BGRP2][16][16];    // 4 KB

    int wg   = xcd_swizzle(blockIdx.x, NBLK2);
    int bg   = wg & (NBG2 - 1);
    int rest = wg >> 6;
    int chunk = rest % ICCH2;
    int n     = rest / ICCH2;
    int b0 = bg * BGRP2;
    int i0 = chunk * CHSZ2;
    int t  = threadIdx.x;

    for (int idx = t; idx < BGRP2 * CHSZ2; idx += 256) {
        int bb = idx / CHSZ2, il = idx - bb * CHSZ2;
        if (ITER0) {
            c_lds[bb][il] = 1.0f / 256.0f;  // softmax of zeros over B=256
        } else {
            int i = i0 + il;
            float be = beta[((size_t)n * BATCH + b0 + bb) * IC + i];
            c_lds[bb][il] = __expf(be) / denom[n * IC + i];
        }
    }
    __syncthreads();

    int o = t & 15, g = t >> 4;
    float acc[BGRP2] = {0.f, 0.f, 0.f, 0.f};
    for (int il = g; il < CHSZ2; il += 16) {   // 24 iterations
        int i = i0 + il;
        const float* wp = w + (((size_t)n * IC + i) * LDIM) * OC + o;
        float w8[8];
#pragma unroll
        for (int l = 0; l < 8; ++l) w8[l] = wp[l * OC];   // 16 o-lanes -> 64B segs
#pragma unroll
        for (int bb = 0; bb < BGRP2; ++bb) {
            const float4* xp = reinterpret_cast<const float4*>(
                x + ((size_t)(b0 + bb) * IC + i) * LDIM);
            float4 xa = xp[0], xb = xp[1];     // broadcast across 16 o-lanes
            float dot = xa.x * w8[0] + xa.y * w8[1] + xa.z * w8[2] + xa.w * w8[3]
                      + xb.x * w8[4] + xb.y * w8[5] + xb.z * w8[6] + xb.w * w8[7];
            acc[bb] += c_lds[bb][il] * dot;
        }
    }
#pragma unroll
    for (int bb = 0; bb < BGRP2; ++bb) red[bb][g][o] = acc[bb];
    __syncthreads();
    if (t < BGRP2 * 16) {
        int bb = t >> 4, oo = t & 15;
        float sum = 0.f;
#pragma unroll
        for (int gg = 0; gg < 16; ++gg) sum += red[bb][gg][oo];
        s_part[((size_t)chunk * NC * BATCH + (size_t)n * BATCH + b0 + bb) * OC + oo] = sum;
    }
}

// ---------------------------------------------------------------------------
// K3: combine 3 partials -> s; global squash scale = sqrt(n2)/(1+n2).
//     Single block, fixed-order reduction. FINAL also writes v to out.
// ---------------------------------------------------------------------------
template<bool FINAL>
__global__ __launch_bounds__(1024) void k3_squash(
    const float* __restrict__ s_part, float* __restrict__ s,
    float* __restrict__ scale_p, float* __restrict__ out)
{
    const int NTOT = NC * BATCH * OC;   // 40960
    __shared__ float red[16];
    __shared__ float sc_sh;
    int t = threadIdx.x;
    float acc = 0.f;
    for (int idx = t; idx < NTOT; idx += 1024) {
        float v = s_part[idx] + s_part[idx + NTOT] + s_part[idx + 2 * NTOT];
        s[idx] = v;
        acc += v * v;
    }
#pragma unroll
    for (int m = 32; m >= 1; m >>= 1) acc += __shfl_xor(acc, m, 64);
    if ((t & 63) == 0) red[t >> 6] = acc;
    __syncthreads();
    if (t == 0) {
        float n2 = 0.f;
#pragma unroll
        for (int k = 0; k < 16; ++k) n2 += red[k];
        float sc = sqrtf(n2) / (1.0f + n2);
        sc_sh = sc;
        *scale_p = sc;
    }
    __syncthreads();
    if (FINAL) {
        float sc = sc_sh;
        for (int idx = t; idx < NTOT; idx += 1024)
            out[idx] = s[idx] * sc;   // re-reads own writes, no sync needed
    }
}

// ---------------------------------------------------------------------------
// K4: beta[n,b,i] (+)= sum_l x[b,i,l] * (sum_o w[n,i,l,o] * v[n,b,o]),
//     v = s*scale inline. Fused softmax denominator: atomicAdd exp(beta_new).
//     256 threads = 32 i-subs x 8 l-lanes.
// ---------------------------------------------------------------------------
template<bool ACCUM>
__global__ __launch_bounds__(256) void k4_beta(
    const float* __restrict__ x, const float* __restrict__ w,
    const float* __restrict__ s, const float* __restrict__ scale_p,
    float* __restrict__ beta, float* __restrict__ denom)
{
    __shared__ float v_lds[BGRP4][OC];
    int wg   = xcd_swizzle(blockIdx.x, NBLK4);
    int bg   = wg & (NBG4 - 1);
    int rest = wg >> 7;
    int chunk = rest & (ICCH4 - 1);
    int n     = rest >> 1;
    int b0 = bg * BGRP4;
    int i0 = chunk * CHSZ4;
    int t  = threadIdx.x;

    if (t < BGRP4 * OC) {
        int bb = t >> 4, o = t & 15;
        v_lds[bb][o] = s[((size_t)n * BATCH + b0 + bb) * OC + o] * (*scale_p);
    }
    __syncthreads();

    float v[BGRP4][OC];
#pragma unroll
    for (int bb = 0; bb < BGRP4; ++bb)
#pragma unroll
        for (int o = 0; o < OC; ++o) v[bb][o] = v_lds[bb][o];

    int l = t & 7, isub = t >> 3;            // 32 i-subs
    for (int it = 0; it < CHSZ4 / 32; ++it) {  // 18 iterations
        int i = i0 + isub + 32 * it;
        const float4* wp = reinterpret_cast<const float4*>(
            w + (((size_t)n * IC + i) * LDIM + l) * OC);  // 8 l-lanes x 64B contiguous
        float4 w0 = wp[0], w1 = wp[1], w2 = wp[2], w3 = wp[3];
        float inc[BGRP4];
#pragma unroll
        for (int bb = 0; bb < BGRP4; ++bb) {
            float wv = w0.x*v[bb][0]  + w0.y*v[bb][1]  + w0.z*v[bb][2]  + w0.w*v[bb][3]
                     + w1.x*v[bb][4]  + w1.y*v[bb][5]  + w1.z*v[bb][6]  + w1.w*v[bb][7]
                     + w2.x*v[bb][8]  + w2.y*v[bb][9]  + w2.z*v[bb][10] + w2.w*v[bb][11]
                     + w3.x*v[bb][12] + w3.y*v[bb][13] + w3.z*v[bb][14] + w3.w*v[bb][15];
            inc[bb] = x[((size_t)(b0 + bb) * IC + i) * LDIM + l] * wv;
        }
        // reduce over the 8 l-lanes (consecutive lanes -> xor masks 1,2,4)
#pragma unroll
        for (int m = 1; m < 8; m <<= 1)
#pragma unroll
            for (int bb = 0; bb < BGRP4; ++bb)
                inc[bb] += __shfl_xor(inc[bb], m, 64);
        if (l == 0) {
#pragma unroll
            for (int bb = 0; bb < BGRP4; ++bb) {
                size_t bi = ((size_t)n * BATCH + b0 + bb) * IC + i;
                float bnew = (ACCUM ? beta[bi] : 0.0f) + inc[bb];
                beta[bi] = bnew;
                atomicAdd(&denom[n * IC + i], __expf(bnew));  // fused softmax denom
            }
        }
    }
}

// ---------------------------------------------------------------------------
extern "C" void kernel_launch(void* const* d_in, const int* in_sizes, int n_in,
                              void* d_out, int out_size, void* d_ws, size_t ws_size,
                              hipStream_t stream)
{
    const float* x = (const float*)d_in[0];   // [256,1152,8]
    const float* w = (const float*)d_in[1];   // [10,1152,8,16]
    float* out = (float*)d_out;               // 40960 floats
    float* ws  = (float*)d_ws;

    float* beta   = ws;                                   // 2,949,120
    float* denom  = beta + (size_t)NC * BATCH * IC;       //    11,520
    float* s      = denom + (size_t)NC * IC;              //    40,960
    float* s_part = s + (size_t)NC * BATCH * OC;          //   122,880
    float* scale  = s_part + (size_t)ICCH2 * NC * BATCH * OC;  //  1
    // total ~12.7 MB

    dim3 blk(256);

    // iter 1 (c uniform)
    k2_s<true><<<NBLK2, blk, 0, stream>>>(x, w, beta, denom, s_part);
    k3_squash<false><<<1, 1024, 0, stream>>>(s_part, s, scale, out);
    hipMemsetAsync(denom, 0, (size_t)NC * IC * sizeof(float), stream);
    k4_beta<false><<<NBLK4, blk, 0, stream>>>(x, w, s, scale, beta, denom);
    // iter 2
    k2_s<false><<<NBLK2, blk, 0, stream>>>(x, w, beta, denom, s_part);
    k3_squash<false><<<1, 1024, 0, stream>>>(s_part, s, scale, out);
    hipMemsetAsync(denom, 0, (size_t)NC * IC * sizeof(float), stream);
    k4_beta<true><<<NBLK4, blk, 0, stream>>>(x, w, s, scale, beta, denom);
    // iter 3
    k2_s<false><<<NBLK2, blk, 0, stream>>>(x, w, beta, denom, s_part);
    k3_squash<true><<<1, 1024, 0, stream>>>(s_part, s, scale, out);
}

// Round 3
// 141.302 us; speedup vs baseline: 3.3412x; 3.3412x over previous
//
#include <hip/hip_runtime.h>
#include <math.h>

#define NC    10
#define BATCH 256
#define IC    1152
#define LDIM  8
#define OC    16

#define NCH   96
#define CH    (IC/NCH)        // 12 i's per block
#define NBLK  (NC*NCH)        // 960 blocks, %8==0 -> bijective XCD swizzle

__device__ __forceinline__ int xcd_swizzle(int bid, int nwg) {
    int cpx = nwg >> 3;
    return (bid & 7) * cpx + (bid >> 3);
}

// ---------------------------------------------------------------------------
// K0: transpose x[b][i][l] -> xT[i][b][l]  (makes thread=b loads coalesced)
// one float4 per thread, output-coalesced.
// ---------------------------------------------------------------------------
__global__ __launch_bounds__(256) void k0_xT(const float* __restrict__ x,
                                             float* __restrict__ xT)
{
    int u = blockIdx.x * 256 + threadIdx.x;       // < 589824
    int i = u >> 9;                               // 512 float4 per i
    int r = u & 511;
    int b = r >> 1, h = r & 1;
    const float4* src = reinterpret_cast<const float4*>(x)
                      + ((size_t)b * IC + i) * 2 + h;
    reinterpret_cast<float4*>(xT)[u] = *src;
}

// ---------------------------------------------------------------------------
// K2: s_part[ch][n][b][o] = sum_{i in chunk} c[n,b,i]*priors[n,b,i,o]
// thread = b. priors recomputed: w lane-uniform (scalar loads), xT coalesced.
// c = exp(betaT)*invd  (or 1/256 on iter 0).
// ---------------------------------------------------------------------------
template<bool ITER0>
__global__ __launch_bounds__(256) void k2_s(
    const float* __restrict__ xT, const float* __restrict__ w,
    const float* __restrict__ betaT, const float* __restrict__ invd,
    float* __restrict__ s_part)
{
    int wg = xcd_swizzle(blockIdx.x, NBLK);
    int n  = wg / NCH, ch = wg % NCH;
    int i0 = ch * CH;
    int t  = threadIdx.x;            // = b

    float sp[OC];
#pragma unroll
    for (int o = 0; o < OC; ++o) sp[o] = 0.f;

    for (int ii = 0; ii < CH; ++ii) {
        int i = i0 + ii;
        const float4* xp = reinterpret_cast<const float4*>(xT)
                         + ((size_t)i * BATCH + t) * 2;
        float4 xa = xp[0], xb = xp[1];
        float xr[8] = {xa.x, xa.y, xa.z, xa.w, xb.x, xb.y, xb.z, xb.w};

        const float* wp = w + ((size_t)n * IC + i) * (LDIM * OC);  // lane-uniform
        float p[OC];
#pragma unroll
        for (int o = 0; o < OC; ++o) p[o] = 0.f;
#pragma unroll
        for (int l = 0; l < LDIM; ++l)
#pragma unroll
            for (int o = 0; o < OC; ++o)
                p[o] += wp[l * OC + o] * xr[l];

        float c;
        if (ITER0) {
            c = 1.0f / 256.0f;
        } else {
            float be = betaT[((size_t)n * IC + i) * BATCH + t];   // coalesced
            c = __expf(be) * invd[n * IC + i];                    // uniform
        }
#pragma unroll
        for (int o = 0; o < OC; ++o) sp[o] += c * p[o];
    }

    float4* dst = reinterpret_cast<float4*>(s_part)
                + (((size_t)ch * NC + n) * BATCH + t) * 4;
    dst[0] = make_float4(sp[0],  sp[1],  sp[2],  sp[3]);
    dst[1] = make_float4(sp[4],  sp[5],  sp[6],  sp[7]);
    dst[2] = make_float4(sp[8],  sp[9],  sp[10], sp[11]);
    dst[3] = make_float4(sp[12], sp[13], sp[14], sp[15]);
}

// ---------------------------------------------------------------------------
// K3a: s[idx] = sum_ch s_part[ch][idx]; per-block partial of n2 (fixed order)
// ---------------------------------------------------------------------------
__global__ __launch_bounds__(256) void k3a(const float* __restrict__ s_part,
                                           float* __restrict__ s,
                                           float* __restrict__ n2_part)
{
    const int NTOT = NC * BATCH * OC;    // 40960
    int idx = blockIdx.x * 256 + threadIdx.x;   // 160 blocks exactly
    float acc = 0.f;
    for (int ch = 0; ch < NCH; ++ch) acc += s_part[(size_t)ch * NTOT + idx];
    s[idx] = acc;
    float q = acc * acc;
#pragma unroll
    for (int m = 32; m >= 1; m >>= 1) q += __shfl_xor(q, m, 64);
    __shared__ float r[4];
    int lane = threadIdx.x & 63, wid = threadIdx.x >> 6;
    if (lane == 0) r[wid] = q;
    __syncthreads();
    if (threadIdx.x == 0) n2_part[blockIdx.x] = r[0] + r[1] + r[2] + r[3];
}

// ---------------------------------------------------------------------------
// K3b: scale = sqrt(n2)/(1+n2), n2 = sum of 160 partials (fixed order)
// ---------------------------------------------------------------------------
__global__ __launch_bounds__(256) void k3b(const float* __restrict__ n2_part,
                                           float* __restrict__ scale_p)
{
    int t = threadIdx.x;
    float q = (t < 160) ? n2_part[t] : 0.f;
#pragma unroll
    for (int m = 32; m >= 1; m >>= 1) q += __shfl_xor(q, m, 64);
    __shared__ float r[4];
    int lane = t & 63, wid = t >> 6;
    if (lane == 0) r[wid] = q;
    __syncthreads();
    if (t == 0) {
        float n2 = r[0] + r[1] + r[2] + r[3];
        *scale_p = sqrtf(n2) / (1.0f + n2);
    }
}

// ---------------------------------------------------------------------------
// K4: betaT[n][i][b] (+)= sum_o priors[n,b,i,o]*v[n,b,o]; v = s*scale.
// thread = b: dot is lane-local (no shfl, no atomics). Block owns all 256 b
// -> softmax denominator reduced in-block, invd written directly (k1 gone).
// ---------------------------------------------------------------------------
template<bool FIRST>
__global__ __launch_bounds__(256) void k4_beta(
    const float* __restrict__ xT, const float* __restrict__ w,
    const float* __restrict__ s, const float* __restrict__ scale_p,
    float* __restrict__ betaT, float* __restrict__ invd)
{
    __shared__ float red[CH][4];
    int wg = xcd_swizzle(blockIdx.x, NBLK);
    int n  = wg / NCH, ch = wg % NCH;
    int i0 = ch * CH;
    int t  = threadIdx.x;            // = b
    int lane = t & 63, wid = t >> 6;

    float sc = *scale_p;
    float v[OC];
    {
        const float4* svp = reinterpret_cast<const float4*>(s)
                          + ((size_t)n * BATCH + t) * 4;
        float4 a = svp[0], b4 = svp[1], c4 = svp[2], d4 = svp[3];
        v[0]=a.x*sc;  v[1]=a.y*sc;  v[2]=a.z*sc;  v[3]=a.w*sc;
        v[4]=b4.x*sc; v[5]=b4.y*sc; v[6]=b4.z*sc; v[7]=b4.w*sc;
        v[8]=c4.x*sc; v[9]=c4.y*sc; v[10]=c4.z*sc;v[11]=c4.w*sc;
        v[12]=d4.x*sc;v[13]=d4.y*sc;v[14]=d4.z*sc;v[15]=d4.w*sc;
    }

    for (int ii = 0; ii < CH; ++ii) {
        int i = i0 + ii;
        const float4* xp = reinterpret_cast<const float4*>(xT)
                         + ((size_t)i * BATCH + t) * 2;
        float4 xa = xp[0], xb = xp[1];
        float xr[8] = {xa.x, xa.y, xa.z, xa.w, xb.x, xb.y, xb.z, xb.w};

        const float* wp = w + ((size_t)n * IC + i) * (LDIM * OC);  // lane-uniform
        float p[OC];
#pragma unroll
        for (int o = 0; o < OC; ++o) p[o] = 0.f;
#pragma unroll
        for (int l = 0; l < LDIM; ++l)
#pragma unroll
            for (int o = 0; o < OC; ++o)
                p[o] += wp[l * OC + o] * xr[l];

        float dot = 0.f;
#pragma unroll
        for (int o = 0; o < OC; ++o) dot += p[o] * v[o];

        size_t bidx = ((size_t)n * IC + i) * BATCH + t;   // coalesced
        float bnew = FIRST ? dot : (betaT[bidx] + dot);
        betaT[bidx] = bnew;

        float e = __expf(bnew);
#pragma unroll
        for (int m = 1; m < 64; m <<= 1) e += __shfl_xor(e, m, 64);
        if (lane == 0) red[ii][wid] = e;
    }
    __syncthreads();
    if (t < CH)
        invd[n * IC + i0 + t] = 1.0f / (red[t][0] + red[t][1] + red[t][2] + red[t][3]);
}

// ---------------------------------------------------------------------------
// K5: out = s * scale (final squash output)
// ---------------------------------------------------------------------------
__global__ __launch_bounds__(256) void k5_out(const float* __restrict__ s,
                                              const float* __restrict__ scale_p,
                                              float* __restrict__ out)
{
    int idx = blockIdx.x * 256 + threadIdx.x;
    out[idx] = s[idx] * (*scale_p);
}

// ---------------------------------------------------------------------------
extern "C" void kernel_launch(void* const* d_in, const int* in_sizes, int n_in,
                              void* d_out, int out_size, void* d_ws, size_t ws_size,
                              hipStream_t stream)
{
    const float* x = (const float*)d_in[0];   // [256,1152,8]
    const float* w = (const float*)d_in[1];   // [10,1152,8,16]
    float* out = (float*)d_out;               // 40960 floats
    float* ws  = (float*)d_ws;

    float* xT      = ws;                                        // 2,359,296
    float* betaT   = xT + (size_t)IC * BATCH * LDIM;            // 2,949,120
    float* invd    = betaT + (size_t)NC * IC * BATCH;           //    11,520
    float* s       = invd + (size_t)NC * IC;                    //    40,960
    float* s_part  = s + (size_t)NC * BATCH * OC;               // 3,932,160
    float* n2_part = s_part + (size_t)NCH * NC * BATCH * OC;    //       160
    float* scale   = n2_part + 160;                             //         1
    // total ~37 MB of workspace

    dim3 blk(256);

    k0_xT<<<2304, blk, 0, stream>>>(x, xT);

    // iter 1 (c uniform = 1/256)
    k2_s<true><<<NBLK, blk, 0, stream>>>(xT, w, betaT, invd, s_part);
    k3a<<<160, blk, 0, stream>>>(s_part, s, n2_part);
    k3b<<<1, blk, 0, stream>>>(n2_part, scale);
    k4_beta<true><<<NBLK, blk, 0, stream>>>(xT, w, s, scale, betaT, invd);
    // iter 2
    k2_s<false><<<NBLK, blk, 0, stream>>>(xT, w, betaT, invd, s_part);
    k3a<<<160, blk, 0, stream>>>(s_part, s, n2_part);
    k3b<<<1, blk, 0, stream>>>(n2_part, scale);
    k4_beta<false><<<NBLK, blk, 0, stream>>>(xT, w, s, scale, betaT, invd);
    // iter 3
    k2_s<false><<<NBLK, blk, 0, stream>>>(xT, w, betaT, invd, s_part);
    k3a<<<160, blk, 0, stream>>>(s_part, s, n2_part);
    k3b<<<1, blk, 0, stream>>>(n2_part, scale);
    k5_out<<<160, blk, 0, stream>>>(s, scale, out);
}